// Round 1
// baseline (356.457 us; speedup 1.0000x reference)
//
#include <hip/hip_runtime.h>
#include <hip/hip_bf16.h>

#define BT 64
#define C  256
#define H  64
#define W  64
#define J  17
#define NP 4
#define HID 128

// bilinear sample of one channel plane p[H][W] at (x, y) in pixel coords,
// padding_mode='zeros', align_corners=True semantics (coords already mapped).
__device__ __forceinline__ float bilin_one(const float* __restrict__ p, float x, float y) {
    float x0f = floorf(x), y0f = floorf(y);
    int x0 = (int)x0f, y0 = (int)y0f;
    int x1 = x0 + 1,  y1 = y0 + 1;
    float wx1 = x - x0f, wx0 = 1.0f - wx1;
    float wy1 = y - y0f, wy0 = 1.0f - wy1;
    bool vx0 = ((unsigned)x0 < (unsigned)W);
    bool vx1 = ((unsigned)x1 < (unsigned)W);
    bool vy0 = ((unsigned)y0 < (unsigned)H);
    bool vy1 = ((unsigned)y1 < (unsigned)H);
    float v00 = (vx0 && vy0) ? p[y0 * W + x0] : 0.0f;
    float v10 = (vx1 && vy0) ? p[y0 * W + x1] : 0.0f;
    float v01 = (vx0 && vy1) ? p[y1 * W + x0] : 0.0f;
    float v11 = (vx1 && vy1) ? p[y1 * W + x1] : 0.0f;
    return v00 * (wx0 * wy0) + v10 * (wx1 * wy0)
         + v01 * (wx0 * wy1) + v11 * (wx1 * wy1);
}

__global__ __launch_bounds__(256) void adaptive_sampler_fused(
        const float* __restrict__ feat,   // [BT, C, H, W]
        const float* __restrict__ kp,     // [BT, J, 2]
        const float* __restrict__ w1,     // [HID, C]
        const float* __restrict__ b1,     // [HID]
        const float* __restrict__ w2,     // [2*NP, HID]
        const float* __restrict__ b2,     // [2*NP]
        float* __restrict__ out)          // [BT, J, NP*C]
{
    const int bj  = blockIdx.x;          // b*J + j
    const int b   = bj / J;
    const int tid = threadIdx.x;         // channel index

    __shared__ float s_seed[C];
    __shared__ float s_h[HID];
    __shared__ float s_off[2 * NP];

    // keypoint grid coords (same for all threads in block)
    const float gx = kp[bj * 2 + 0];
    const float gy = kp[bj * 2 + 1];

    const float px = (gx + 1.0f) * 0.5f * (float)(W - 1);
    const float py = (gy + 1.0f) * 0.5f * (float)(H - 1);

    const float* fb = feat + (size_t)b * C * H * W;
    const float* plane = fb + (size_t)tid * H * W;

    // ---- 1. seed sample: thread tid handles channel tid ----
    s_seed[tid] = bilin_one(plane, px, py);
    __syncthreads();

    // ---- 2. MLP layer 1: 128 outputs, thread o computes h[o] ----
    if (tid < HID) {
        const float4* wrow = (const float4*)(w1 + tid * C);
        float acc = 0.0f;
        #pragma unroll 8
        for (int c4 = 0; c4 < C / 4; ++c4) {
            float4 wv = wrow[c4];
            acc += wv.x * s_seed[c4 * 4 + 0];
            acc += wv.y * s_seed[c4 * 4 + 1];
            acc += wv.z * s_seed[c4 * 4 + 2];
            acc += wv.w * s_seed[c4 * 4 + 3];
        }
        s_h[tid] = fmaxf(acc + b1[tid], 0.0f);
    }
    __syncthreads();

    // ---- 3. MLP layer 2: 8 outputs (2*NP) ----
    if (tid < 2 * NP) {
        const float4* wrow = (const float4*)(w2 + tid * HID);
        float acc = 0.0f;
        #pragma unroll 8
        for (int k4 = 0; k4 < HID / 4; ++k4) {
            float4 wv = wrow[k4];
            acc += wv.x * s_h[k4 * 4 + 0];
            acc += wv.y * s_h[k4 * 4 + 1];
            acc += wv.z * s_h[k4 * 4 + 2];
            acc += wv.w * s_h[k4 * 4 + 3];
        }
        s_off[tid] = acc + b2[tid];
    }
    __syncthreads();

    // ---- 4. deformed samples: 4 points, thread tid = channel ----
    const float sx = 2.0f / (float)(W - 1);
    const float sy = 2.0f / (float)(H - 1);
    float* outp = out + (size_t)bj * NP * C + tid;
    #pragma unroll
    for (int n = 0; n < NP; ++n) {
        const float ngx = gx + s_off[2 * n + 0] * sx;
        const float ngy = gy + s_off[2 * n + 1] * sy;
        const float npx = (ngx + 1.0f) * 0.5f * (float)(W - 1);
        const float npy = (ngy + 1.0f) * 0.5f * (float)(H - 1);
        outp[n * C] = bilin_one(plane, npx, npy);
    }
}

extern "C" void kernel_launch(void* const* d_in, const int* in_sizes, int n_in,
                              void* d_out, int out_size, void* d_ws, size_t ws_size,
                              hipStream_t stream) {
    const float* feat = (const float*)d_in[0];
    const float* kp   = (const float*)d_in[1];
    const float* w1   = (const float*)d_in[2];
    const float* b1   = (const float*)d_in[3];
    const float* w2   = (const float*)d_in[4];
    const float* b2   = (const float*)d_in[5];
    float* out = (float*)d_out;

    dim3 grid(BT * J);
    dim3 block(256);
    adaptive_sampler_fused<<<grid, block, 0, stream>>>(feat, kp, w1, b1, w2, b2, out);
}